// Round 2
// baseline (2148.023 us; speedup 1.0000x reference)
//
#include <hip/hip_runtime.h>
#include <cstdint>
#include <cstddef>

typedef __attribute__((ext_vector_type(8))) short s8v;   // 8 x bf16 (4 VGPRs)
typedef __attribute__((ext_vector_type(4))) float f4v;   // 4 x f32

constexpr int Lc = 8, Bc = 8, Sc = 2048, Dc = 1024, Hc = 16, Fc = 4096;

__device__ __forceinline__ unsigned short f2bf(float f) {
    unsigned int u = __float_as_uint(f);
    u = (u + 0x7FFFu + ((u >> 16) & 1u)) >> 16;   // RNE
    return (unsigned short)u;
}

// async global->LDS, 16B per lane. LDS dest = wave-uniform base + lane*16.
__device__ __forceinline__ void gload16(const unsigned short* g, unsigned short* l) {
    __builtin_amdgcn_global_load_lds(
        (const __attribute__((address_space(1))) unsigned int*)g,
        (__attribute__((address_space(3))) unsigned int*)l, 16, 0, 0);
}

// ---------- transpose + cast: fp32 [L][R][C] -> bf16 [L][C][R] ----------
__global__ __launch_bounds__(256) void transpose_cast(
    const float* __restrict__ in, unsigned short* __restrict__ out, int R, int C) {
    __shared__ float tile[32][33];
    int l = blockIdx.z;
    int r0 = blockIdx.y << 5, c0 = blockIdx.x << 5;
    const float* ip = in + (size_t)l * R * C;
    unsigned short* op = out + (size_t)l * R * C;
    int tx = threadIdx.x & 31, ty = threadIdx.x >> 5;   // 32 x 8
#pragma unroll
    for (int i = 0; i < 4; i++)
        tile[ty + i * 8][tx] = ip[(size_t)(r0 + ty + i * 8) * C + (c0 + tx)];
    __syncthreads();
#pragma unroll
    for (int i = 0; i < 4; i++)
        op[(size_t)(c0 + ty + i * 8) * R + (r0 + tx)] = f2bf(tile[tx][ty + i * 8]);
}

// ---------- bf16 transpose: [B][S][D] slice (b, :, h*64+dh) -> vT [B][H][64][S] ----------
__global__ __launch_bounds__(256) void transpose_v(
    const unsigned short* __restrict__ in, unsigned short* __restrict__ out) {
    __shared__ unsigned short t[32][33];
    int bh = blockIdx.z, b = bh >> 4, h = bh & 15;
    int s0 = blockIdx.x << 5, d0 = blockIdx.y << 5;
    int tx = threadIdx.x & 31, ty = threadIdx.x >> 5;
    const unsigned short* ip = in + (size_t)(b * Sc + s0) * Dc + (h << 6) + d0;
#pragma unroll
    for (int i = 0; i < 4; i++)
        t[ty + i * 8][tx] = ip[(size_t)(ty + i * 8) * Dc + tx];
    __syncthreads();
    unsigned short* op = out + ((size_t)(b * Hc + h) * 64 + d0) * Sc + s0;
#pragma unroll
    for (int i = 0; i < 4; i++)
        op[(size_t)(ty + i * 8) * Sc + tx] = t[tx][ty + i * 8];
}

// ---------- layernorm: fp32 [B][S][D] -> bf16, per-batch routed params ----------
__global__ __launch_bounds__(256) void ln_kernel(
    const float* __restrict__ x, const float* __restrict__ sc, const float* __restrict__ bi,
    const int* __restrict__ idx, unsigned short* __restrict__ out) {
    int row = blockIdx.x;           // b*S + s
    int b = row >> 11;              // S = 2048
    int l = idx[b];
    const float* xr = x + (size_t)row * Dc;
    int t = threadIdx.x;            // 256 threads x 4 floats = 1024
    float4 xv = *(const float4*)(xr + t * 4);
    float s = xv.x + xv.y + xv.z + xv.w;
    float ss = xv.x * xv.x + xv.y * xv.y + xv.z * xv.z + xv.w * xv.w;
#pragma unroll
    for (int off = 32; off; off >>= 1) { s += __shfl_xor(s, off); ss += __shfl_xor(ss, off); }
    __shared__ float red[2][4];
    int w = t >> 6, lane = t & 63;
    if (lane == 0) { red[0][w] = s; red[1][w] = ss; }
    __syncthreads();
    float tot = red[0][0] + red[0][1] + red[0][2] + red[0][3];
    float tots = red[1][0] + red[1][1] + red[1][2] + red[1][3];
    float mean = tot * (1.0f / Dc);
    float var = tots * (1.0f / Dc) - mean * mean;
    float r = rsqrtf(var + 1e-5f);
    float4 s4 = *(const float4*)(sc + (size_t)l * Dc + t * 4);
    float4 b4 = *(const float4*)(bi + (size_t)l * Dc + t * 4);
    ushort4 o;
    o.x = f2bf((xv.x - mean) * r * s4.x + b4.x);
    o.y = f2bf((xv.y - mean) * r * s4.y + b4.y);
    o.z = f2bf((xv.z - mean) * r * s4.z + b4.z);
    o.w = f2bf((xv.w - mean) * r * s4.w + b4.w);
    *(ushort4*)(out + (size_t)row * Dc + t * 4) = o;
}

// ---------- MFMA GEMM (m97 structure): C[b] = A[b] @ Wt[idx[b]]^T + bias ----------
// Wt is [L][N][K] bf16. LDS tiles 128x32 unpadded, staged via global_load_lds w=16,
// chunk XOR-swizzled by row&3 to cut ds_read_b128 bank conflicts.
// EPI: 0=bf16 store, 1=gelu->bf16, 2=resid add->fp32
template <int EPI>
__global__ __launch_bounds__(256) void gemm_kernel(
    const unsigned short* __restrict__ A, const unsigned short* __restrict__ Wt,
    const float* __restrict__ bias, const int* __restrict__ idx,
    const float* __restrict__ resid, void* __restrict__ out, int M, int N, int K) {
    int b = blockIdx.z;
    int l = idx[b];
    int m0 = blockIdx.y << 7, n0 = blockIdx.x << 7;
    const unsigned short* Ab = A + (size_t)b * M * K;
    const unsigned short* Wl = Wt + (size_t)l * N * K;
    __shared__ alignas(16) unsigned short As[128 * 32];
    __shared__ alignas(16) unsigned short Bs[128 * 32];
    int tid = threadIdx.x, w = tid >> 6, lane = tid & 63, quad = lane >> 4, lr = lane & 15;
    int wm = (w >> 1) << 6, wn = (w & 1) << 6;   // wave -> 64x64 region
    f4v acc[4][4];
#pragma unroll
    for (int i = 0; i < 4; i++)
#pragma unroll
        for (int j = 0; j < 4; j++) acc[i][j] = 0.f;

    // staging: thread -> (row = c*64 + w*16 + lane/4, physical chunk = lane&3).
    // physical chunk p of row r holds logical chunk p ^ (r&3).
    int srow = (w << 4) + (lane >> 2);
    int schunk = (lane & 3) ^ ((lane >> 2) & 3);
    const unsigned short* ag0 = Ab + (size_t)(m0 + srow) * K + (schunk << 3);
    const unsigned short* ag1 = Ab + (size_t)(m0 + 64 + srow) * K + (schunk << 3);
    const unsigned short* bg0 = Wl + (size_t)(n0 + srow) * K + (schunk << 3);
    const unsigned short* bg1 = Wl + (size_t)(n0 + 64 + srow) * K + (schunk << 3);
    unsigned short* la0 = As + ((w << 4) << 5);          // + lane*16B by HW
    unsigned short* la1 = As + ((64 + (w << 4)) << 5);
    unsigned short* lb0 = Bs + ((w << 4) << 5);
    unsigned short* lb1 = Bs + ((64 + (w << 4)) << 5);
    int fchunk = (quad ^ (lr & 3)) << 3;                 // frag read swizzle (shorts)

    for (int k0 = 0; k0 < K; k0 += 32) {
        __syncthreads();                       // prev iter LDS reads done
        gload16(ag0 + k0, la0);
        gload16(ag1 + k0, la1);
        gload16(bg0 + k0, lb0);
        gload16(bg1 + k0, lb1);
        __syncthreads();                       // vmcnt(0) drain + tiles visible
        s8v af[4], bf[4];
#pragma unroll
        for (int i = 0; i < 4; i++) af[i] = *(const s8v*)&As[((wm + i * 16 + lr) << 5) + fchunk];
#pragma unroll
        for (int j = 0; j < 4; j++) bf[j] = *(const s8v*)&Bs[((wn + j * 16 + lr) << 5) + fchunk];
#pragma unroll
        for (int i = 0; i < 4; i++)
#pragma unroll
            for (int j = 0; j < 4; j++)
                acc[i][j] = __builtin_amdgcn_mfma_f32_16x16x32_bf16(af[i], bf[j], acc[i][j], 0, 0, 0);
    }

    float bj[4];
#pragma unroll
    for (int j = 0; j < 4; j++) bj[j] = bias[(size_t)l * N + (n0 + wn + j * 16 + lr)];
    size_t obase = (size_t)b * M * N;
#pragma unroll
    for (int i = 0; i < 4; i++) {
#pragma unroll
        for (int r = 0; r < 4; r++) {
            int gm = m0 + wm + i * 16 + quad * 4 + r;   // C/D: row = quad*4+reg
            size_t rowoff = obase + (size_t)gm * N;
#pragma unroll
            for (int j = 0; j < 4; j++) {
                int gn = n0 + wn + j * 16 + lr;         // C/D: col = lane&15
                float val = acc[i][j][r] + bj[j];
                if constexpr (EPI == 0) {
                    ((unsigned short*)out)[rowoff + gn] = f2bf(val);
                } else if constexpr (EPI == 1) {
                    float g = 0.5f * val * (1.0f + tanhf(0.7978845608f * (val + 0.044715f * val * val * val)));
                    ((unsigned short*)out)[rowoff + gn] = f2bf(g);
                } else {
                    ((float*)out)[rowoff + gn] = resid[rowoff + gn] + val;
                }
            }
        }
    }
}

// ---------- flash attention, S^T formulation: no LDS / no barriers in K-loop ----------
// Wave owns 16 q (q = lane&15). S^T = K·Q^T via MFMA (A=K rows, B=Q rows).
// Key permutation: tile t row i -> key (t>>1)*32 + (i>>2)*8 + (t&1)*4 + (i&3), so the
// P^T C-layout registers are exactly the B-fragments (k=quad*8+j) for the PV MFMA.
// PV: O^T = V^T · P^T with V^T A-frags as contiguous 16B loads from pre-transposed vT.
__global__ __launch_bounds__(256) void flash_kernel(
    const unsigned short* __restrict__ qm, const unsigned short* __restrict__ km,
    const unsigned short* __restrict__ vT, unsigned short* __restrict__ om) {
    const int b = blockIdx.z, h = blockIdx.y, q0 = blockIdx.x << 6;
    const int tid = threadIdx.x, w = tid >> 6, lane = tid & 63, quad = lane >> 4, lr = lane & 15;
    const size_t bS = (size_t)b * Sc;
    const int hoff = h << 6;

    const unsigned short* qr = qm + (bS + q0 + (w << 4) + lr) * (size_t)Dc + hoff + (quad << 3);
    s8v bq0 = *(const s8v*)qr;           // Q B-frag, dh 0..31
    s8v bq1 = *(const s8v*)(qr + 32);    // dh 32..63
    const int krow_off = ((lr >> 2) << 3) + (lr & 3);             // permuted key row for A-frag
    const unsigned short* kbase = km + bS * (size_t)Dc + hoff + (quad << 3);
    const unsigned short* vbase = vT + ((size_t)(b * Hc + h) * 64 + lr) * Sc + (quad << 3);

    f4v accO[4];                          // O^T tiles: dh = d*16+quad*4+r, q = lr
#pragma unroll
    for (int d = 0; d < 4; d++) accO[d] = 0.f;
    float m_s = -3e38f, l_s = 0.f;        // per-lane softmax state (one q per lane)

    for (int kv0 = 0; kv0 < Sc; kv0 += 64) {
        f4v st[4];
#pragma unroll
        for (int t = 0; t < 4; t++) {
            const unsigned short* kr =
                kbase + (size_t)(kv0 + ((t >> 1) << 5) + ((t & 1) << 2) + krow_off) * Dc;
            s8v a0 = *(const s8v*)kr;
            s8v a1 = *(const s8v*)(kr + 32);
            f4v c;
            c = 0.f;
            c = __builtin_amdgcn_mfma_f32_16x16x32_bf16(a0, bq0, c, 0, 0, 0);
            c = __builtin_amdgcn_mfma_f32_16x16x32_bf16(a1, bq1, c, 0, 0, 0);
            st[t] = c * 0.125f;           // 1/sqrt(64)
        }
        float lm = -3e38f;
#pragma unroll
        for (int t = 0; t < 4; t++)
#pragma unroll
            for (int r = 0; r < 4; r++) lm = fmaxf(lm, st[t][r]);
        lm = fmaxf(lm, __shfl_xor(lm, 16));
        lm = fmaxf(lm, __shfl_xor(lm, 32));
        float mn = fmaxf(m_s, lm);
        float alpha = __expf(m_s - mn);
        m_s = mn;
        float ps[4][4], ls = 0.f;
#pragma unroll
        for (int t = 0; t < 4; t++)
#pragma unroll
            for (int r = 0; r < 4; r++) { ps[t][r] = __expf(st[t][r] - mn); ls += ps[t][r]; }
        ls += __shfl_xor(ls, 16);
        ls += __shfl_xor(ls, 32);
        l_s = l_s * alpha + ls;
#pragma unroll
        for (int d = 0; d < 4; d++) accO[d] *= alpha;
        s8v pf0, pf1;                     // P^T B-frags: keys kv0+c*32+quad*8+j, q=lr
#pragma unroll
        for (int j = 0; j < 4; j++) {
            pf0[j] = (short)f2bf(ps[0][j]);
            pf0[4 + j] = (short)f2bf(ps[1][j]);
            pf1[j] = (short)f2bf(ps[2][j]);
            pf1[4 + j] = (short)f2bf(ps[3][j]);
        }
#pragma unroll
        for (int d = 0; d < 4; d++) {
            const unsigned short* vp = vbase + ((size_t)(d << 4)) * Sc + kv0;
            s8v v0 = *(const s8v*)vp;          // V^T A-frag: dh=d*16+lr, keys quad*8+j
            s8v v1 = *(const s8v*)(vp + 32);   // keys 32+quad*8+j
            accO[d] = __builtin_amdgcn_mfma_f32_16x16x32_bf16(v0, pf0, accO[d], 0, 0, 0);
            accO[d] = __builtin_amdgcn_mfma_f32_16x16x32_bf16(v1, pf1, accO[d], 0, 0, 0);
        }
    }

    // epilogue: O^T (C-layout) -> LDS -> row-major O, coalesced store
    __shared__ unsigned short Ot[4][64][17];
    float inv_l = 1.0f / l_s;
#pragma unroll
    for (int d = 0; d < 4; d++)
#pragma unroll
        for (int r = 0; r < 4; r++)
            Ot[w][(d << 4) + (quad << 2) + r][lr] = f2bf(accO[d][r] * inv_l);
    __syncthreads();
    int q = lane >> 2, ch = lane & 3;     // 4 threads cover one q-row's 64 dh
    unsigned short* orow = om + (bS + q0 + (w << 4) + q) * (size_t)Dc + hoff + (ch << 4);
    s8v o0, o1;
#pragma unroll
    for (int e = 0; e < 8; e++) {
        o0[e] = (short)Ot[w][(ch << 4) + e][q];
        o1[e] = (short)Ot[w][(ch << 4) + 8 + e][q];
    }
    *(s8v*)orow = o0;
    *(s8v*)(orow + 8) = o1;
}

extern "C" void kernel_launch(void* const* d_in, const int* in_sizes, int n_in,
                              void* d_out, int out_size, void* d_ws, size_t ws_size,
                              hipStream_t stream) {
    const float* x  = (const float*)d_in[0];
    const int* idx  = (const int*)d_in[1];
    const float* Wq = (const float*)d_in[2];  const float* bq  = (const float*)d_in[3];
    const float* Wk = (const float*)d_in[4];  const float* bk  = (const float*)d_in[5];
    const float* Wv = (const float*)d_in[6];  const float* bv  = (const float*)d_in[7];
    const float* Wo = (const float*)d_in[8];  const float* bo  = (const float*)d_in[9];
    const float* s1 = (const float*)d_in[10]; const float* b1n = (const float*)d_in[11];
    const float* s2 = (const float*)d_in[12]; const float* b2n = (const float*)d_in[13];
    const float* W1 = (const float*)d_in[14]; const float* bf1 = (const float*)d_in[15];
    const float* W2 = (const float*)d_in[16]; const float* bf2 = (const float*)d_in[17];

    // workspace layout (bf16 elements unless noted); total ~416 MB
    const size_t eDD  = (size_t)Lc * Dc * Dc;   // 2^23
    const size_t eDF  = (size_t)Lc * Dc * Fc;   // 2^25
    const size_t eBSD = (size_t)Bc * Sc * Dc;   // 2^24
    unsigned short* Wtq = (unsigned short*)d_ws;
    unsigned short* Wtk = Wtq + eDD;
    unsigned short* Wtv = Wtk + eDD;
    unsigned short* Wto = Wtv + eDD;
    unsigned short* Wt1 = Wto + eDD;            // eDF
    unsigned short* Wt2 = Wt1 + eDF;            // eDF
    unsigned short* hb  = Wt2 + eDF;            // eBSD (LN out; later aliased as vT)
    unsigned short* qb  = hb + eBSD;
    unsigned short* kb  = qb + eBSD;
    unsigned short* vb  = kb + eBSD;
    unsigned short* ab  = vb + eBSD;            // attn output
    float* x2           = (float*)(ab + eBSD);  // eBSD floats
    unsigned short* fb  = qb;                   // FFN hidden reuses q..attn (4*eBSD == B*S*F)
    unsigned short* vTb = hb;                   // vT aliases hb (dead after QKV gemms)

    dim3 blk(256);
    // 1) weight transpose+cast
    transpose_cast<<<dim3(Dc / 32, Dc / 32, Lc), blk, 0, stream>>>(Wq, Wtq, Dc, Dc);
    transpose_cast<<<dim3(Dc / 32, Dc / 32, Lc), blk, 0, stream>>>(Wk, Wtk, Dc, Dc);
    transpose_cast<<<dim3(Dc / 32, Dc / 32, Lc), blk, 0, stream>>>(Wv, Wtv, Dc, Dc);
    transpose_cast<<<dim3(Dc / 32, Dc / 32, Lc), blk, 0, stream>>>(Wo, Wto, Dc, Dc);
    transpose_cast<<<dim3(Fc / 32, Dc / 32, Lc), blk, 0, stream>>>(W1, Wt1, Dc, Fc);
    transpose_cast<<<dim3(Dc / 32, Fc / 32, Lc), blk, 0, stream>>>(W2, Wt2, Fc, Dc);
    // 2) LN1
    ln_kernel<<<Bc * Sc, blk, 0, stream>>>(x, s1, b1n, idx, hb);
    // 3) QKV projections
    gemm_kernel<0><<<dim3(Dc / 128, Sc / 128, Bc), blk, 0, stream>>>(hb, Wtq, bq, idx, nullptr, qb, Sc, Dc, Dc);
    gemm_kernel<0><<<dim3(Dc / 128, Sc / 128, Bc), blk, 0, stream>>>(hb, Wtk, bk, idx, nullptr, kb, Sc, Dc, Dc);
    gemm_kernel<0><<<dim3(Dc / 128, Sc / 128, Bc), blk, 0, stream>>>(hb, Wtv, bv, idx, nullptr, vb, Sc, Dc, Dc);
    // 3b) V -> V^T [B][H][64][S] (hb is dead now; reuse as vT)
    transpose_v<<<dim3(Sc / 32, 2, Bc * Hc), blk, 0, stream>>>(vb, vTb);
    // 4) attention
    flash_kernel<<<dim3(Sc / 64, Hc, Bc), blk, 0, stream>>>(qb, kb, vTb, ab);
    // 5) output projection + residual -> x2 (fp32)
    gemm_kernel<2><<<dim3(Dc / 128, Sc / 128, Bc), blk, 0, stream>>>(ab, Wto, bo, idx, x, x2, Sc, Dc, Dc);
    // 6) LN2 (overwrites vT alias — attention is done with it)
    ln_kernel<<<Bc * Sc, blk, 0, stream>>>(x2, s2, b2n, idx, hb);
    // 7) FFN up + gelu
    gemm_kernel<1><<<dim3(Fc / 128, Sc / 128, Bc), blk, 0, stream>>>(hb, Wt1, bf1, idx, nullptr, fb, Sc, Fc, Dc);
    // 8) FFN down + residual -> d_out (fp32)
    gemm_kernel<2><<<dim3(Dc / 128, Sc / 128, Bc), blk, 0, stream>>>(fb, Wt2, bf2, idx, x2, (float*)d_out, Sc, Dc, Fc);
}